// Round 5
// baseline (725.934 us; speedup 1.0000x reference)
//
#include <hip/hip_runtime.h>
#include <hip/hip_bf16.h>

#define T_TOKENS 4096
#define DM 1024
#define DF 4096
#define NE 8
#define MAXROWS 9216   // 8192 + 8*128 padding

typedef float f32x4 __attribute__((ext_vector_type(4)));
typedef short bf16x8 __attribute__((ext_vector_type(8)));

__device__ __forceinline__ unsigned short f2bf(float f) {
    union { float f; unsigned int u; } v; v.f = f;
    unsigned int r = v.u + 0x7fffu + ((v.u >> 16) & 1u);
    return (unsigned short)(r >> 16);
}

// async global->LDS, 16B per lane; LDS dest = wave-uniform base + lane*16
__device__ __forceinline__ void g2l16(const void* g, void* l) {
    __builtin_amdgcn_global_load_lds(
        (const __attribute__((address_space(1))) void*)g,
        (__attribute__((address_space(3))) void*)l, 16, 0, 0);
}

// ---------------- gating: logits -> top2 (softmax monotone, skip it) ----------------
__global__ __launch_bounds__(256) void gate_kernel(
    const float* __restrict__ x, const float* __restrict__ Wg, const float* __restrict__ bg,
    int* __restrict__ counts, int* __restrict__ topk)
{
    int wave = threadIdx.x >> 6;
    int lane = threadIdx.x & 63;
    int t = blockIdx.x * 4 + wave;
    float acc[NE];
#pragma unroll
    for (int e = 0; e < NE; e++) acc[e] = 0.f;
    const float* xr = x + (size_t)t * DM;
#pragma unroll
    for (int i = 0; i < DM / 64; i++) {
        int d = lane + i * 64;
        float xv = xr[d];
        const float4* wg = (const float4*)(Wg + d * NE);
        float4 w0 = wg[0], w1 = wg[1];
        acc[0] += xv * w0.x; acc[1] += xv * w0.y; acc[2] += xv * w0.z; acc[3] += xv * w0.w;
        acc[4] += xv * w1.x; acc[5] += xv * w1.y; acc[6] += xv * w1.z; acc[7] += xv * w1.w;
    }
#pragma unroll
    for (int e = 0; e < NE; e++) {
#pragma unroll
        for (int off = 32; off > 0; off >>= 1)
            acc[e] += __shfl_down(acc[e], off);
    }
    if (lane == 0) {
        float lg[NE];
#pragma unroll
        for (int e = 0; e < NE; e++) lg[e] = acc[e] + bg[e];
        int b1i = 0; float b1v = lg[0];
        for (int e = 1; e < NE; e++) if (lg[e] > b1v) { b1v = lg[e]; b1i = e; }
        int b2i = -1; float b2v = -1e30f;
        for (int e = 0; e < NE; e++) {
            if (e == b1i) continue;
            if (b2i < 0 || lg[e] > b2v) { b2v = lg[e]; b2i = e; }
        }
        topk[t * 2 + 0] = b1i;
        topk[t * 2 + 1] = b2i;
        atomicAdd(&counts[b1i], 1);
        atomicAdd(&counts[b2i], 1);
    }
}

// ---------------- per-expert token lists, segments padded to 128 rows ----------------
__global__ __launch_bounds__(256) void scatter_kernel(
    const int* __restrict__ counts, const int* __restrict__ topk,
    int* __restrict__ offsets, int* __restrict__ list)
{
    __shared__ int offs[NE + 1];
    __shared__ int cur[NE];
    if (threadIdx.x == 0) {
        int s = 0;
        for (int e = 0; e < NE; e++) {
            offs[e] = s; offsets[e] = s;
            s += (counts[e] + 127) & ~127;
        }
        offs[NE] = s; offsets[NE] = s;
    }
    if (threadIdx.x < NE) cur[threadIdx.x] = 0;
    __syncthreads();
    for (int i = threadIdx.x; i < T_TOKENS * 2; i += 256) {
        int e = topk[i];
        int pos = atomicAdd(&cur[e], 1);
        list[offs[e] + pos] = i >> 1;
    }
    __syncthreads();
    for (int e = 0; e < NE; e++) {
        int s = offs[e] + counts[e];
        int t = offs[e + 1];
        for (int i = s + threadIdx.x; i < t; i += 256) list[i] = -1;
    }
}

// ---------------- x fp32 -> bf16 ----------------
__global__ __launch_bounds__(256) void cvt_x_kernel(
    const float* __restrict__ x, unsigned short* __restrict__ xb)
{
    int i = (blockIdx.x * 256 + threadIdx.x) * 4;
    float4 v = *(const float4*)(x + i);
    unsigned short o[4] = { f2bf(v.x), f2bf(v.y), f2bf(v.z), f2bf(v.w) };
    *(uint2*)(xb + i) = *(const uint2*)o;
}

// ---------------- W [e][K][N] fp32 -> [e][N][K] bf16 (tile transpose via LDS) ------
__global__ __launch_bounds__(256) void tr_cvt_kernel(
    const float* __restrict__ src, unsigned short* __restrict__ dst, int K, int N)
{
    const int e = blockIdx.z;
    src += (size_t)e * K * N;
    dst += (size_t)e * N * K;
    const int n0 = blockIdx.x * 64, k0 = blockIdx.y * 64;
    __shared__ unsigned short tile[64][68];
    const int t = threadIdx.x;
    const int c4 = (t & 15) * 4;   // n offset within tile
    const int kr = t >> 4;         // 0..15
#pragma unroll
    for (int r = 0; r < 4; r++) {
        int k = kr + r * 16;
        float4 v = *(const float4*)(src + (size_t)(k0 + k) * N + n0 + c4);
        tile[c4 + 0][k] = f2bf(v.x);
        tile[c4 + 1][k] = f2bf(v.y);
        tile[c4 + 2][k] = f2bf(v.z);
        tile[c4 + 3][k] = f2bf(v.w);
    }
    __syncthreads();
    const int kx = (t & 15) * 4, ny = t >> 4;
#pragma unroll
    for (int r = 0; r < 4; r++) {
        int n = ny + r * 16;
        *(uint2*)(dst + (size_t)(n0 + n) * K + k0 + kx) = *(const uint2*)&tile[n][kx];
    }
}

// ---------------- GEMM1: H = relu(gather(xb) @ W1T^T + b1), all experts fused ------
// r0 structure (BK=32, 2 barriers/step), 128x128 tile, XCD-chunked swizzle
__global__ __launch_bounds__(256) void gemm1_kernel(
    const unsigned short* __restrict__ xb, const unsigned short* __restrict__ W1T,
    const float* __restrict__ b1, const int* __restrict__ offsets,
    const int* __restrict__ list, unsigned short* __restrict__ H)
{
    // bijective XCD-chunked swizzle: 2304 blocks, chunk = 288 per XCD
    const int bid = blockIdx.x;
    const int swz = (bid & 7) * (2304 >> 3) + (bid >> 3);
    const int bx = swz % (MAXROWS / 128);   // 72, x-fastest: same-expert runs share B
    const int by = swz / (MAXROWS / 128);

    const int total = offsets[NE];
    const int row0 = bx * 128;
    if (row0 >= total) return;
    int e = 0;
    while (row0 >= offsets[e + 1]) e++;
    const int n0 = by * 128;

    __shared__ unsigned short Asm[128 * 32];
    __shared__ unsigned short Bsm[128 * 32];

    const int tid = threadIdx.x;
    const int w = tid >> 6, lane = tid & 63;
    const int quad = lane >> 4, l16 = lane & 15;
    const int wm = w >> 1, wn = w & 1;

    const int sr = lane >> 2;                              // row within 16-row chunk
    const int sc = (((lane & 3) ^ ((sr >> 1) & 3))) * 8;   // swizzled k source offset
    const int qx8 = (quad ^ ((l16 >> 1) & 3)) * 8;         // swizzled k read offset

    const int ra1 = 32 * w + sr, ra2 = ra1 + 16;
    int t1 = list[row0 + ra1]; if (t1 < 0) t1 = 0;
    int t2 = list[row0 + ra2]; if (t2 < 0) t2 = 0;
    const unsigned short* gA1 = xb + (size_t)t1 * DM + sc;
    const unsigned short* gA2 = xb + (size_t)t2 * DM + sc;
    const unsigned short* Wb = W1T + (size_t)e * DF * DM;
    const unsigned short* gB1 = Wb + (size_t)(n0 + 32 * w + sr) * DM + sc;
    const unsigned short* gB2 = gB1 + (size_t)16 * DM;
    unsigned short* lA1 = Asm + (2 * w) * 512;
    unsigned short* lA2 = Asm + (2 * w + 1) * 512;
    unsigned short* lB1 = Bsm + (2 * w) * 512;
    unsigned short* lB2 = Bsm + (2 * w + 1) * 512;

    f32x4 acc[4][4];
#pragma unroll
    for (int i = 0; i < 4; i++)
#pragma unroll
        for (int j = 0; j < 4; j++) acc[i][j] = (f32x4){0.f, 0.f, 0.f, 0.f};

    for (int kk = 0; kk < DM; kk += 32) {
        g2l16(gA1 + kk, lA1);
        g2l16(gA2 + kk, lA2);
        g2l16(gB1 + kk, lB1);
        g2l16(gB2 + kk, lB2);
        __syncthreads();
        bf16x8 af[4];
#pragma unroll
        for (int i = 0; i < 4; i++)
            af[i] = *(const bf16x8*)&Asm[(wm * 64 + i * 16 + l16) * 32 + qx8];
#pragma unroll
        for (int j = 0; j < 4; j++) {
            bf16x8 bfv = *(const bf16x8*)&Bsm[(wn * 64 + j * 16 + l16) * 32 + qx8];
#pragma unroll
            for (int i = 0; i < 4; i++)
                acc[i][j] = __builtin_amdgcn_mfma_f32_16x16x32_bf16(af[i], bfv, acc[i][j], 0, 0, 0);
        }
        __syncthreads();
    }

    const float* bias = b1 + e * DF;
#pragma unroll
    for (int j = 0; j < 4; j++) {
        int n = n0 + wn * 64 + j * 16 + l16;
        float bj = bias[n];
#pragma unroll
        for (int i = 0; i < 4; i++) {
            int row = row0 + wm * 64 + i * 16 + quad * 4;
#pragma unroll
            for (int r = 0; r < 4; r++) {
                float v = acc[i][j][r] + bj;
                v = fmaxf(v, 0.f);
                H[(size_t)(row + r) * DF + n] = f2bf(v);
            }
        }
    }
}

// ---------------- GEMM2: out[tok] += H @ W2T^T + b2, all experts fused -------------
// 64x128 tile (4.5 blocks/CU: TLP-based latency hiding), BK=32, XCD-chunked swizzle
__global__ __launch_bounds__(256) void gemm2_kernel(
    const unsigned short* __restrict__ H, const unsigned short* __restrict__ W2T,
    const float* __restrict__ b2, const int* __restrict__ offsets,
    const int* __restrict__ list, float* __restrict__ out)
{
    // bijective XCD-chunked swizzle: 1152 blocks, chunk = 144 per XCD
    const int bid = blockIdx.x;
    const int swz = (bid & 7) * (1152 >> 3) + (bid >> 3);
    const int bx = swz % (MAXROWS / 64);    // 144, x-fastest: same-expert runs share B
    const int by = swz / (MAXROWS / 64);

    const int total = offsets[NE];
    const int row0 = bx * 64;
    if (row0 >= total) return;
    int e = 0;
    while (row0 >= offsets[e + 1]) e++;
    const int n0 = by * 128;

    __shared__ unsigned short sA[64 * 32];    // 4 KB
    __shared__ unsigned short sB[128 * 32];   // 8 KB

    const int tid = threadIdx.x;
    const int w = tid >> 6, lane = tid & 63;
    const int quad = lane >> 4, l16 = lane & 15;
    const int wm = w >> 1, wn = w & 1;        // wave tile: 32 rows x 64 cols

    const int sr = lane >> 2;
    const int sc = (((lane & 3) ^ ((sr >> 1) & 3))) * 8;
    const int qx8 = (quad ^ ((l16 >> 1) & 3)) * 8;

    // A: 4 chunks of 16 rows, one per wave. B: 8 chunks, two per wave.
    const unsigned short* gA1 = H + (size_t)(row0 + 16 * w + sr) * DF + sc;
    const unsigned short* Wb = W2T + (size_t)e * DM * DF;
    const unsigned short* gB1 = Wb + (size_t)(n0 + 32 * w + sr) * DF + sc;
    const unsigned short* gB2 = gB1 + (size_t)16 * DF;
    unsigned short* lA1 = sA + w * 512;
    unsigned short* lB1 = sB + (2 * w) * 512;
    unsigned short* lB2 = sB + (2 * w + 1) * 512;

    f32x4 acc[2][4];
#pragma unroll
    for (int i = 0; i < 2; i++)
#pragma unroll
        for (int j = 0; j < 4; j++) acc[i][j] = (f32x4){0.f, 0.f, 0.f, 0.f};

    for (int kk = 0; kk < DF; kk += 32) {
        g2l16(gA1 + kk, lA1);
        g2l16(gB1 + kk, lB1);
        g2l16(gB2 + kk, lB2);
        __syncthreads();
        bf16x8 af[2];
#pragma unroll
        for (int i = 0; i < 2; i++)
            af[i] = *(const bf16x8*)&sA[(wm * 32 + i * 16 + l16) * 32 + qx8];
#pragma unroll
        for (int j = 0; j < 4; j++) {
            bf16x8 bfv = *(const bf16x8*)&sB[(wn * 64 + j * 16 + l16) * 32 + qx8];
#pragma unroll
            for (int i = 0; i < 2; i++)
                acc[i][j] = __builtin_amdgcn_mfma_f32_16x16x32_bf16(af[i], bfv, acc[i][j], 0, 0, 0);
        }
        __syncthreads();
    }

    const float* bias = b2 + e * DM;
#pragma unroll
    for (int j = 0; j < 4; j++) {
        int n = n0 + wn * 64 + j * 16 + l16;
        float bj = bias[n];
#pragma unroll
        for (int i = 0; i < 2; i++) {
            int row = row0 + wm * 32 + i * 16 + quad * 4;
#pragma unroll
            for (int r = 0; r < 4; r++) {
                int tk = list[row + r];
                if (tk >= 0)
                    atomicAdd(&out[(size_t)tk * DM + n], acc[i][j][r] + bj);
            }
        }
    }
}

extern "C" void kernel_launch(void* const* d_in, const int* in_sizes, int n_in,
                              void* d_out, int out_size, void* d_ws, size_t ws_size,
                              hipStream_t stream)
{
    const float* x  = (const float*)d_in[0];
    const float* Wg = (const float*)d_in[1];
    const float* bg = (const float*)d_in[2];
    const float* W1 = (const float*)d_in[3];
    const float* b1 = (const float*)d_in[4];
    const float* W2 = (const float*)d_in[5];
    const float* b2 = (const float*)d_in[6];
    float* out = (float*)d_out;

    char* ws = (char*)d_ws;
    int* counts  = (int*)(ws + 0);            // 8 ints
    int* offsets = (int*)(ws + 64);           // 9 ints
    int* topk    = (int*)(ws + 256);          // 8192 ints
    int* list    = (int*)(ws + 33024);        // 9216 ints
    unsigned short* xb = (unsigned short*)(ws + (1u << 20));           // 8 MB
    unsigned short* WT = (unsigned short*)(ws + (16u << 20));          // 64 MB (W1T then W2T)
    unsigned short* Hb = (unsigned short*)(ws + (80u << 20));          // 75.5 MB

    hipMemsetAsync(counts, 0, NE * sizeof(int), stream);
    hipMemsetAsync(d_out, 0, (size_t)out_size * sizeof(float), stream);

    gate_kernel<<<T_TOKENS / 4, 256, 0, stream>>>(x, Wg, bg, counts, topk);
    scatter_kernel<<<1, 256, 0, stream>>>(counts, topk, offsets, list);
    cvt_x_kernel<<<T_TOKENS * DM / 1024, 256, 0, stream>>>(x, xb);

    // W1: [e][K=DM][N=DF] -> [e][DF][DM]
    tr_cvt_kernel<<<dim3(DF / 64, DM / 64, NE), 256, 0, stream>>>(W1, WT, DM, DF);
    gemm1_kernel<<<dim3((MAXROWS / 128) * (DF / 128)), 256, 0, stream>>>(
        xb, WT, b1, offsets, list, Hb);

    // W2: [e][K=DF][N=DM] -> [e][DM][DF]  (reuses WT buffer; stream serializes)
    tr_cvt_kernel<<<dim3(DM / 64, DF / 64, NE), 256, 0, stream>>>(W2, WT, DF, DM);
    gemm2_kernel<<<dim3((MAXROWS / 64) * (DM / 128)), 256, 0, stream>>>(
        Hb, WT, b2, offsets, list, out);
}

// Round 6
// 666.766 us; speedup vs baseline: 1.0887x; 1.0887x over previous
//
#include <hip/hip_runtime.h>
#include <hip/hip_bf16.h>

#define T_TOKENS 4096
#define DM 1024
#define DF 4096
#define NE 8
#define MAXROWS 9216   // 8192 + 8*128 padding

typedef float f32x4 __attribute__((ext_vector_type(4)));
typedef short bf16x8 __attribute__((ext_vector_type(8)));

__device__ __forceinline__ unsigned short f2bf(float f) {
    union { float f; unsigned int u; } v; v.f = f;
    unsigned int r = v.u + 0x7fffu + ((v.u >> 16) & 1u);
    return (unsigned short)(r >> 16);
}

// async global->LDS, 16B per lane; LDS dest = wave-uniform base + lane*16
__device__ __forceinline__ void g2l16(const void* g, void* l) {
    __builtin_amdgcn_global_load_lds(
        (const __attribute__((address_space(1))) void*)g,
        (__attribute__((address_space(3))) void*)l, 16, 0, 0);
}

// ---------------- gating: logits -> top2 (softmax monotone, skip it) ----------------
__global__ __launch_bounds__(256) void gate_kernel(
    const float* __restrict__ x, const float* __restrict__ Wg, const float* __restrict__ bg,
    int* __restrict__ counts, int* __restrict__ topk)
{
    int wave = threadIdx.x >> 6;
    int lane = threadIdx.x & 63;
    int t = blockIdx.x * 4 + wave;
    float acc[NE];
#pragma unroll
    for (int e = 0; e < NE; e++) acc[e] = 0.f;
    const float* xr = x + (size_t)t * DM;
#pragma unroll
    for (int i = 0; i < DM / 64; i++) {
        int d = lane + i * 64;
        float xv = xr[d];
        const float4* wg = (const float4*)(Wg + d * NE);
        float4 w0 = wg[0], w1 = wg[1];
        acc[0] += xv * w0.x; acc[1] += xv * w0.y; acc[2] += xv * w0.z; acc[3] += xv * w0.w;
        acc[4] += xv * w1.x; acc[5] += xv * w1.y; acc[6] += xv * w1.z; acc[7] += xv * w1.w;
    }
#pragma unroll
    for (int e = 0; e < NE; e++) {
#pragma unroll
        for (int off = 32; off > 0; off >>= 1)
            acc[e] += __shfl_down(acc[e], off);
    }
    if (lane == 0) {
        float lg[NE];
#pragma unroll
        for (int e = 0; e < NE; e++) lg[e] = acc[e] + bg[e];
        int b1i = 0; float b1v = lg[0];
        for (int e = 1; e < NE; e++) if (lg[e] > b1v) { b1v = lg[e]; b1i = e; }
        int b2i = -1; float b2v = -1e30f;
        for (int e = 0; e < NE; e++) {
            if (e == b1i) continue;
            if (b2i < 0 || lg[e] > b2v) { b2v = lg[e]; b2i = e; }
        }
        topk[t * 2 + 0] = b1i;
        topk[t * 2 + 1] = b2i;
        atomicAdd(&counts[b1i], 1);
        atomicAdd(&counts[b2i], 1);
    }
}

// ---------------- per-expert token lists, segments padded to 128 rows ----------------
__global__ __launch_bounds__(256) void scatter_kernel(
    const int* __restrict__ counts, const int* __restrict__ topk,
    int* __restrict__ offsets, int* __restrict__ list)
{
    __shared__ int offs[NE + 1];
    __shared__ int cur[NE];
    if (threadIdx.x == 0) {
        int s = 0;
        for (int e = 0; e < NE; e++) {
            offs[e] = s; offsets[e] = s;
            s += (counts[e] + 127) & ~127;
        }
        offs[NE] = s; offsets[NE] = s;
    }
    if (threadIdx.x < NE) cur[threadIdx.x] = 0;
    __syncthreads();
    for (int i = threadIdx.x; i < T_TOKENS * 2; i += 256) {
        int e = topk[i];
        int pos = atomicAdd(&cur[e], 1);
        list[offs[e] + pos] = i >> 1;
    }
    __syncthreads();
    for (int e = 0; e < NE; e++) {
        int s = offs[e] + counts[e];
        int t = offs[e + 1];
        for (int i = s + threadIdx.x; i < t; i += 256) list[i] = -1;
    }
}

// ---------------- x fp32 -> bf16 ----------------
__global__ __launch_bounds__(256) void cvt_x_kernel(
    const float* __restrict__ x, unsigned short* __restrict__ xb)
{
    int i = (blockIdx.x * 256 + threadIdx.x) * 4;
    float4 v = *(const float4*)(x + i);
    unsigned short o[4] = { f2bf(v.x), f2bf(v.y), f2bf(v.z), f2bf(v.w) };
    *(uint2*)(xb + i) = *(const uint2*)o;
}

// ---------------- W [e][K][N] fp32 -> [e][N][K] bf16 (tile transpose via LDS) ------
__global__ __launch_bounds__(256) void tr_cvt_kernel(
    const float* __restrict__ src, unsigned short* __restrict__ dst, int K, int N)
{
    const int e = blockIdx.z;
    src += (size_t)e * K * N;
    dst += (size_t)e * N * K;
    const int n0 = blockIdx.x * 64, k0 = blockIdx.y * 64;
    __shared__ unsigned short tile[64][68];
    const int t = threadIdx.x;
    const int c4 = (t & 15) * 4;   // n offset within tile
    const int kr = t >> 4;         // 0..15
#pragma unroll
    for (int r = 0; r < 4; r++) {
        int k = kr + r * 16;
        float4 v = *(const float4*)(src + (size_t)(k0 + k) * N + n0 + c4);
        tile[c4 + 0][k] = f2bf(v.x);
        tile[c4 + 1][k] = f2bf(v.y);
        tile[c4 + 2][k] = f2bf(v.z);
        tile[c4 + 3][k] = f2bf(v.w);
    }
    __syncthreads();
    const int kx = (t & 15) * 4, ny = t >> 4;
#pragma unroll
    for (int r = 0; r < 4; r++) {
        int n = ny + r * 16;
        *(uint2*)(dst + (size_t)(n0 + n) * K + k0 + kx) = *(const uint2*)&tile[n][kx];
    }
}

// ---------------- GEMM1: H = relu(gather(xb) @ W1T^T + b1), all experts fused ------
// r0 structure (128x128, BK=32); expert-major-per-XCD work order:
// XCD x gets W-range [288x, 288x+288) = row-blocks [9x,9x+9) x 32 n-panels
// => per-XCD B working set = ~one expert's W1T panel (L2-resident K-slices)
__global__ __launch_bounds__(256) void gemm1_kernel(
    const unsigned short* __restrict__ xb, const unsigned short* __restrict__ W1T,
    const float* __restrict__ b1, const int* __restrict__ offsets,
    const int* __restrict__ list, unsigned short* __restrict__ H)
{
    const int bid = blockIdx.x;                 // 2304 = 8 * 288
    const int W = (bid & 7) * 288 + (bid >> 3); // bijective
    const int bx = W >> 5;                      // row-block 0..71 (expert-contiguous)
    const int by = W & 31;                      // n-panel 0..31

    const int total = offsets[NE];
    const int row0 = bx * 128;
    if (row0 >= total) return;
    int e = 0;
    while (row0 >= offsets[e + 1]) e++;
    const int n0 = by * 128;

    __shared__ unsigned short Asm[128 * 32];
    __shared__ unsigned short Bsm[128 * 32];

    const int tid = threadIdx.x;
    const int w = tid >> 6, lane = tid & 63;
    const int quad = lane >> 4, l16 = lane & 15;
    const int wm = w >> 1, wn = w & 1;

    const int sr = lane >> 2;                              // row within 16-row chunk
    const int sc = (((lane & 3) ^ ((sr >> 1) & 3))) * 8;   // swizzled k source offset
    const int qx8 = (quad ^ ((l16 >> 1) & 3)) * 8;         // swizzled k read offset

    const int ra1 = 32 * w + sr, ra2 = ra1 + 16;
    int t1 = list[row0 + ra1]; if (t1 < 0) t1 = 0;
    int t2 = list[row0 + ra2]; if (t2 < 0) t2 = 0;
    const unsigned short* gA1 = xb + (size_t)t1 * DM + sc;
    const unsigned short* gA2 = xb + (size_t)t2 * DM + sc;
    const unsigned short* Wb = W1T + (size_t)e * DF * DM;
    const unsigned short* gB1 = Wb + (size_t)(n0 + 32 * w + sr) * DM + sc;
    const unsigned short* gB2 = gB1 + (size_t)16 * DM;
    unsigned short* lA1 = Asm + (2 * w) * 512;
    unsigned short* lA2 = Asm + (2 * w + 1) * 512;
    unsigned short* lB1 = Bsm + (2 * w) * 512;
    unsigned short* lB2 = Bsm + (2 * w + 1) * 512;

    f32x4 acc[4][4];
#pragma unroll
    for (int i = 0; i < 4; i++)
#pragma unroll
        for (int j = 0; j < 4; j++) acc[i][j] = (f32x4){0.f, 0.f, 0.f, 0.f};

    for (int kk = 0; kk < DM; kk += 32) {
        g2l16(gA1 + kk, lA1);
        g2l16(gA2 + kk, lA2);
        g2l16(gB1 + kk, lB1);
        g2l16(gB2 + kk, lB2);
        __syncthreads();
        bf16x8 af[4];
#pragma unroll
        for (int i = 0; i < 4; i++)
            af[i] = *(const bf16x8*)&Asm[(wm * 64 + i * 16 + l16) * 32 + qx8];
#pragma unroll
        for (int j = 0; j < 4; j++) {
            bf16x8 bfv = *(const bf16x8*)&Bsm[(wn * 64 + j * 16 + l16) * 32 + qx8];
#pragma unroll
            for (int i = 0; i < 4; i++)
                acc[i][j] = __builtin_amdgcn_mfma_f32_16x16x32_bf16(af[i], bfv, acc[i][j], 0, 0, 0);
        }
        __syncthreads();
    }

    const float* bias = b1 + e * DF;
#pragma unroll
    for (int j = 0; j < 4; j++) {
        int n = n0 + wn * 64 + j * 16 + l16;
        float bj = bias[n];
#pragma unroll
        for (int i = 0; i < 4; i++) {
            int row = row0 + wm * 64 + i * 16 + quad * 4;
#pragma unroll
            for (int r = 0; r < 4; r++) {
                float v = acc[i][j][r] + bj;
                v = fmaxf(v, 0.f);
                H[(size_t)(row + r) * DF + n] = f2bf(v);
            }
        }
    }
}

// ---------------- GEMM2: out[tok] += H @ W2T^T + b2, all experts fused -------------
// r0 structure (128x128, BK=32); expert-major-per-XCD work order:
// XCD x gets W-range [72x, 72x+72) = row-blocks [9x,9x+9) x 8 n-panels
__global__ __launch_bounds__(256) void gemm2_kernel(
    const unsigned short* __restrict__ H, const unsigned short* __restrict__ W2T,
    const float* __restrict__ b2, const int* __restrict__ offsets,
    const int* __restrict__ list, float* __restrict__ out)
{
    const int bid = blockIdx.x;                // 576 = 8 * 72
    const int W = (bid & 7) * 72 + (bid >> 3); // bijective
    const int bx = W >> 3;                     // row-block 0..71 (expert-contiguous)
    const int by = W & 7;                      // n-panel 0..7

    const int total = offsets[NE];
    const int row0 = bx * 128;
    if (row0 >= total) return;
    int e = 0;
    while (row0 >= offsets[e + 1]) e++;
    const int n0 = by * 128;

    __shared__ unsigned short Asm[128 * 32];
    __shared__ unsigned short Bsm[128 * 32];

    const int tid = threadIdx.x;
    const int w = tid >> 6, lane = tid & 63;
    const int quad = lane >> 4, l16 = lane & 15;
    const int wm = w >> 1, wn = w & 1;

    const int sr = lane >> 2;
    const int sc = (((lane & 3) ^ ((sr >> 1) & 3))) * 8;
    const int qx8 = (quad ^ ((l16 >> 1) & 3)) * 8;

    const unsigned short* gA1 = H + (size_t)(row0 + 32 * w + sr) * DF + sc;
    const unsigned short* gA2 = gA1 + (size_t)16 * DF;
    const unsigned short* Wb = W2T + (size_t)e * DM * DF;
    const unsigned short* gB1 = Wb + (size_t)(n0 + 32 * w + sr) * DF + sc;
    const unsigned short* gB2 = gB1 + (size_t)16 * DF;
    unsigned short* lA1 = Asm + (2 * w) * 512;
    unsigned short* lA2 = Asm + (2 * w + 1) * 512;
    unsigned short* lB1 = Bsm + (2 * w) * 512;
    unsigned short* lB2 = Bsm + (2 * w + 1) * 512;

    f32x4 acc[4][4];
#pragma unroll
    for (int i = 0; i < 4; i++)
#pragma unroll
        for (int j = 0; j < 4; j++) acc[i][j] = (f32x4){0.f, 0.f, 0.f, 0.f};

    for (int kk = 0; kk < DF; kk += 32) {
        g2l16(gA1 + kk, lA1);
        g2l16(gA2 + kk, lA2);
        g2l16(gB1 + kk, lB1);
        g2l16(gB2 + kk, lB2);
        __syncthreads();
        bf16x8 af[4];
#pragma unroll
        for (int i = 0; i < 4; i++)
            af[i] = *(const bf16x8*)&Asm[(wm * 64 + i * 16 + l16) * 32 + qx8];
#pragma unroll
        for (int j = 0; j < 4; j++) {
            bf16x8 bfv = *(const bf16x8*)&Bsm[(wn * 64 + j * 16 + l16) * 32 + qx8];
#pragma unroll
            for (int i = 0; i < 4; i++)
                acc[i][j] = __builtin_amdgcn_mfma_f32_16x16x32_bf16(af[i], bfv, acc[i][j], 0, 0, 0);
        }
        __syncthreads();
    }

    const float* bias = b2 + e * DM;
#pragma unroll
    for (int j = 0; j < 4; j++) {
        int n = n0 + wn * 64 + j * 16 + l16;
        float bj = bias[n];
#pragma unroll
        for (int i = 0; i < 4; i++) {
            int row = row0 + wm * 64 + i * 16 + quad * 4;
#pragma unroll
            for (int r = 0; r < 4; r++) {
                int tk = list[row + r];
                if (tk >= 0)
                    atomicAdd(&out[(size_t)tk * DM + n], acc[i][j][r] + bj);
            }
        }
    }
}

extern "C" void kernel_launch(void* const* d_in, const int* in_sizes, int n_in,
                              void* d_out, int out_size, void* d_ws, size_t ws_size,
                              hipStream_t stream)
{
    const float* x  = (const float*)d_in[0];
    const float* Wg = (const float*)d_in[1];
    const float* bg = (const float*)d_in[2];
    const float* W1 = (const float*)d_in[3];
    const float* b1 = (const float*)d_in[4];
    const float* W2 = (const float*)d_in[5];
    const float* b2 = (const float*)d_in[6];
    float* out = (float*)d_out;

    char* ws = (char*)d_ws;
    int* counts  = (int*)(ws + 0);            // 8 ints
    int* offsets = (int*)(ws + 64);           // 9 ints
    int* topk    = (int*)(ws + 256);          // 8192 ints
    int* list    = (int*)(ws + 33024);        // 9216 ints
    unsigned short* xb = (unsigned short*)(ws + (1u << 20));           // 8 MB
    unsigned short* WT = (unsigned short*)(ws + (16u << 20));          // 64 MB (W1T then W2T)
    unsigned short* Hb = (unsigned short*)(ws + (80u << 20));          // 75.5 MB

    hipMemsetAsync(counts, 0, NE * sizeof(int), stream);
    hipMemsetAsync(d_out, 0, (size_t)out_size * sizeof(float), stream);

    gate_kernel<<<T_TOKENS / 4, 256, 0, stream>>>(x, Wg, bg, counts, topk);
    scatter_kernel<<<1, 256, 0, stream>>>(counts, topk, offsets, list);
    cvt_x_kernel<<<T_TOKENS * DM / 1024, 256, 0, stream>>>(x, xb);

    // W1: [e][K=DM][N=DF] -> [e][DF][DM]
    tr_cvt_kernel<<<dim3(DF / 64, DM / 64, NE), 256, 0, stream>>>(W1, WT, DM, DF);
    gemm1_kernel<<<dim3((MAXROWS / 128) * (DF / 128)), 256, 0, stream>>>(
        xb, WT, b1, offsets, list, Hb);

    // W2: [e][K=DF][N=DM] -> [e][DM][DF]  (reuses WT buffer; stream serializes)
    tr_cvt_kernel<<<dim3(DM / 64, DF / 64, NE), 256, 0, stream>>>(W2, WT, DF, DM);
    gemm2_kernel<<<dim3((MAXROWS / 128) * (DM / 128)), 256, 0, stream>>>(
        Hb, WT, b2, offsets, list, out);
}

// Round 7
// 664.441 us; speedup vs baseline: 1.0925x; 1.0035x over previous
//
#include <hip/hip_runtime.h>
#include <hip/hip_bf16.h>

#define T_TOKENS 4096
#define DM 1024
#define DF 4096
#define NE 8
#define MAXROWS 9216   // 8192 + 8*128 padding

typedef float f32x4 __attribute__((ext_vector_type(4)));
typedef short bf16x8 __attribute__((ext_vector_type(8)));

__device__ __forceinline__ unsigned short f2bf(float f) {
    union { float f; unsigned int u; } v; v.f = f;
    unsigned int r = v.u + 0x7fffu + ((v.u >> 16) & 1u);
    return (unsigned short)(r >> 16);
}

// async global->LDS, 16B per lane; LDS dest = wave-uniform base + lane*16
__device__ __forceinline__ void g2l16(const void* g, void* l) {
    __builtin_amdgcn_global_load_lds(
        (const __attribute__((address_space(1))) void*)g,
        (__attribute__((address_space(3))) void*)l, 16, 0, 0);
}

// ------- gating: logits -> top2 (softmax monotone, skip it); also emits x in bf16 ----
__global__ __launch_bounds__(256) void gate_kernel(
    const float* __restrict__ x, const float* __restrict__ Wg, const float* __restrict__ bg,
    int* __restrict__ counts, int* __restrict__ topk, unsigned short* __restrict__ xb)
{
    int wave = threadIdx.x >> 6;
    int lane = threadIdx.x & 63;
    int t = blockIdx.x * 4 + wave;
    float acc[NE];
#pragma unroll
    for (int e = 0; e < NE; e++) acc[e] = 0.f;
    const float* xr = x + (size_t)t * DM;
    unsigned short* xbr = xb + (size_t)t * DM;
#pragma unroll
    for (int i = 0; i < DM / 64; i++) {
        int d = lane + i * 64;
        float xv = xr[d];
        xbr[d] = f2bf(xv);                    // fused cvt_x (same rounding as before)
        const float4* wg = (const float4*)(Wg + d * NE);
        float4 w0 = wg[0], w1 = wg[1];
        acc[0] += xv * w0.x; acc[1] += xv * w0.y; acc[2] += xv * w0.z; acc[3] += xv * w0.w;
        acc[4] += xv * w1.x; acc[5] += xv * w1.y; acc[6] += xv * w1.z; acc[7] += xv * w1.w;
    }
#pragma unroll
    for (int e = 0; e < NE; e++) {
#pragma unroll
        for (int off = 32; off > 0; off >>= 1)
            acc[e] += __shfl_down(acc[e], off);
    }
    if (lane == 0) {
        float lg[NE];
#pragma unroll
        for (int e = 0; e < NE; e++) lg[e] = acc[e] + bg[e];
        int b1i = 0; float b1v = lg[0];
        for (int e = 1; e < NE; e++) if (lg[e] > b1v) { b1v = lg[e]; b1i = e; }
        int b2i = -1; float b2v = -1e30f;
        for (int e = 0; e < NE; e++) {
            if (e == b1i) continue;
            if (b2i < 0 || lg[e] > b2v) { b2v = lg[e]; b2i = e; }
        }
        topk[t * 2 + 0] = b1i;
        topk[t * 2 + 1] = b2i;
        atomicAdd(&counts[b1i], 1);
        atomicAdd(&counts[b2i], 1);
    }
}

// ---------------- per-expert token lists, segments padded to 128 rows ----------------
__global__ __launch_bounds__(256) void scatter_kernel(
    const int* __restrict__ counts, const int* __restrict__ topk,
    int* __restrict__ offsets, int* __restrict__ list)
{
    __shared__ int offs[NE + 1];
    __shared__ int cur[NE];
    if (threadIdx.x == 0) {
        int s = 0;
        for (int e = 0; e < NE; e++) {
            offs[e] = s; offsets[e] = s;
            s += (counts[e] + 127) & ~127;
        }
        offs[NE] = s; offsets[NE] = s;
    }
    if (threadIdx.x < NE) cur[threadIdx.x] = 0;
    __syncthreads();
    for (int i = threadIdx.x; i < T_TOKENS * 2; i += 256) {
        int e = topk[i];
        int pos = atomicAdd(&cur[e], 1);
        list[offs[e] + pos] = i >> 1;
    }
    __syncthreads();
    for (int e = 0; e < NE; e++) {
        int s = offs[e] + counts[e];
        int t = offs[e + 1];
        for (int i = s + threadIdx.x; i < t; i += 256) list[i] = -1;
    }
}

// ---------------- W [e][K][N] fp32 -> [e][N][K] bf16 (tile transpose via LDS) ------
// 256(k) x 64(n) tiles: float4 reads (256B segments), 512B-contiguous uint4 stores
// (32 lanes cover one full row segment per instruction)
__global__ __launch_bounds__(256) void tr_cvt_kernel(
    const float* __restrict__ src, unsigned short* __restrict__ dst, int K, int N)
{
    const int e = blockIdx.z;
    src += (size_t)e * K * N;
    dst += (size_t)e * N * K;
    const int n0 = blockIdx.x * 64, k0 = blockIdx.y * 256;
    __shared__ unsigned short tile[64][264];   // 33.8 KB, +8 pad
    const int t = threadIdx.x;
    const int c4 = (t & 15) * 4;   // n offset within tile
    const int kr = t >> 4;         // 0..15
#pragma unroll
    for (int r = 0; r < 16; r++) {
        int k = kr + r * 16;
        float4 v = *(const float4*)(src + (size_t)(k0 + k) * N + n0 + c4);
        tile[c4 + 0][k] = f2bf(v.x);
        tile[c4 + 1][k] = f2bf(v.y);
        tile[c4 + 2][k] = f2bf(v.z);
        tile[c4 + 3][k] = f2bf(v.w);
    }
    __syncthreads();
    const int rg = t >> 5;         // 0..7: row within group of 8
    const int c = t & 31;          // 32 x uint4 = 512B per row
#pragma unroll
    for (int r = 0; r < 8; r++) {
        int n = rg + r * 8;
        *(uint4*)(dst + (size_t)(n0 + n) * K + k0 + c * 8) = *(const uint4*)&tile[n][c * 8];
    }
}

// ---------------- GEMM1: H = relu(gather(xb) @ W1T^T + b1), all experts fused ------
// r0 structure (128x128, BK=32); expert-major-per-XCD work order:
// XCD x gets W-range [288x, 288x+288) = row-blocks [9x,9x+9) x 32 n-panels
// => per-XCD B working set = ~one expert's W1T panel (L2-resident K-slices)
__global__ __launch_bounds__(256) void gemm1_kernel(
    const unsigned short* __restrict__ xb, const unsigned short* __restrict__ W1T,
    const float* __restrict__ b1, const int* __restrict__ offsets,
    const int* __restrict__ list, unsigned short* __restrict__ H)
{
    const int bid = blockIdx.x;                 // 2304 = 8 * 288
    const int W = (bid & 7) * 288 + (bid >> 3); // bijective
    const int bx = W >> 5;                      // row-block 0..71 (expert-contiguous)
    const int by = W & 31;                      // n-panel 0..31

    const int total = offsets[NE];
    const int row0 = bx * 128;
    if (row0 >= total) return;
    int e = 0;
    while (row0 >= offsets[e + 1]) e++;
    const int n0 = by * 128;

    __shared__ unsigned short Asm[128 * 32];
    __shared__ unsigned short Bsm[128 * 32];

    const int tid = threadIdx.x;
    const int w = tid >> 6, lane = tid & 63;
    const int quad = lane >> 4, l16 = lane & 15;
    const int wm = w >> 1, wn = w & 1;

    const int sr = lane >> 2;                              // row within 16-row chunk
    const int sc = (((lane & 3) ^ ((sr >> 1) & 3))) * 8;   // swizzled k source offset
    const int qx8 = (quad ^ ((l16 >> 1) & 3)) * 8;         // swizzled k read offset

    const int ra1 = 32 * w + sr, ra2 = ra1 + 16;
    int t1 = list[row0 + ra1]; if (t1 < 0) t1 = 0;
    int t2 = list[row0 + ra2]; if (t2 < 0) t2 = 0;
    const unsigned short* gA1 = xb + (size_t)t1 * DM + sc;
    const unsigned short* gA2 = xb + (size_t)t2 * DM + sc;
    const unsigned short* Wb = W1T + (size_t)e * DF * DM;
    const unsigned short* gB1 = Wb + (size_t)(n0 + 32 * w + sr) * DM + sc;
    const unsigned short* gB2 = gB1 + (size_t)16 * DM;
    unsigned short* lA1 = Asm + (2 * w) * 512;
    unsigned short* lA2 = Asm + (2 * w + 1) * 512;
    unsigned short* lB1 = Bsm + (2 * w) * 512;
    unsigned short* lB2 = Bsm + (2 * w + 1) * 512;

    f32x4 acc[4][4];
#pragma unroll
    for (int i = 0; i < 4; i++)
#pragma unroll
        for (int j = 0; j < 4; j++) acc[i][j] = (f32x4){0.f, 0.f, 0.f, 0.f};

    for (int kk = 0; kk < DM; kk += 32) {
        g2l16(gA1 + kk, lA1);
        g2l16(gA2 + kk, lA2);
        g2l16(gB1 + kk, lB1);
        g2l16(gB2 + kk, lB2);
        __syncthreads();
        bf16x8 af[4];
#pragma unroll
        for (int i = 0; i < 4; i++)
            af[i] = *(const bf16x8*)&Asm[(wm * 64 + i * 16 + l16) * 32 + qx8];
#pragma unroll
        for (int j = 0; j < 4; j++) {
            bf16x8 bfv = *(const bf16x8*)&Bsm[(wn * 64 + j * 16 + l16) * 32 + qx8];
#pragma unroll
            for (int i = 0; i < 4; i++)
                acc[i][j] = __builtin_amdgcn_mfma_f32_16x16x32_bf16(af[i], bfv, acc[i][j], 0, 0, 0);
        }
        __syncthreads();
    }

    const float* bias = b1 + e * DF;
#pragma unroll
    for (int j = 0; j < 4; j++) {
        int n = n0 + wn * 64 + j * 16 + l16;
        float bj = bias[n];
#pragma unroll
        for (int i = 0; i < 4; i++) {
            int row = row0 + wm * 64 + i * 16 + quad * 4;
#pragma unroll
            for (int r = 0; r < 4; r++) {
                float v = acc[i][j][r] + bj;
                v = fmaxf(v, 0.f);
                H[(size_t)(row + r) * DF + n] = f2bf(v);
            }
        }
    }
}

// ---------------- GEMM2: out[tok] += H @ W2T^T + b2, all experts fused -------------
// r0 structure (128x128, BK=32); expert-major-per-XCD work order:
// XCD x gets W-range [72x, 72x+72) = row-blocks [9x,9x+9) x 8 n-panels
__global__ __launch_bounds__(256) void gemm2_kernel(
    const unsigned short* __restrict__ H, const unsigned short* __restrict__ W2T,
    const float* __restrict__ b2, const int* __restrict__ offsets,
    const int* __restrict__ list, float* __restrict__ out)
{
    const int bid = blockIdx.x;                // 576 = 8 * 72
    const int W = (bid & 7) * 72 + (bid >> 3); // bijective
    const int bx = W >> 3;                     // row-block 0..71 (expert-contiguous)
    const int by = W & 7;                      // n-panel 0..7

    const int total = offsets[NE];
    const int row0 = bx * 128;
    if (row0 >= total) return;
    int e = 0;
    while (row0 >= offsets[e + 1]) e++;
    const int n0 = by * 128;

    __shared__ unsigned short Asm[128 * 32];
    __shared__ unsigned short Bsm[128 * 32];

    const int tid = threadIdx.x;
    const int w = tid >> 6, lane = tid & 63;
    const int quad = lane >> 4, l16 = lane & 15;
    const int wm = w >> 1, wn = w & 1;

    const int sr = lane >> 2;
    const int sc = (((lane & 3) ^ ((sr >> 1) & 3))) * 8;
    const int qx8 = (quad ^ ((l16 >> 1) & 3)) * 8;

    const unsigned short* gA1 = H + (size_t)(row0 + 32 * w + sr) * DF + sc;
    const unsigned short* gA2 = gA1 + (size_t)16 * DF;
    const unsigned short* Wb = W2T + (size_t)e * DM * DF;
    const unsigned short* gB1 = Wb + (size_t)(n0 + 32 * w + sr) * DF + sc;
    const unsigned short* gB2 = gB1 + (size_t)16 * DF;
    unsigned short* lA1 = Asm + (2 * w) * 512;
    unsigned short* lA2 = Asm + (2 * w + 1) * 512;
    unsigned short* lB1 = Bsm + (2 * w) * 512;
    unsigned short* lB2 = Bsm + (2 * w + 1) * 512;

    f32x4 acc[4][4];
#pragma unroll
    for (int i = 0; i < 4; i++)
#pragma unroll
        for (int j = 0; j < 4; j++) acc[i][j] = (f32x4){0.f, 0.f, 0.f, 0.f};

    for (int kk = 0; kk < DF; kk += 32) {
        g2l16(gA1 + kk, lA1);
        g2l16(gA2 + kk, lA2);
        g2l16(gB1 + kk, lB1);
        g2l16(gB2 + kk, lB2);
        __syncthreads();
        bf16x8 af[4];
#pragma unroll
        for (int i = 0; i < 4; i++)
            af[i] = *(const bf16x8*)&Asm[(wm * 64 + i * 16 + l16) * 32 + qx8];
#pragma unroll
        for (int j = 0; j < 4; j++) {
            bf16x8 bfv = *(const bf16x8*)&Bsm[(wn * 64 + j * 16 + l16) * 32 + qx8];
#pragma unroll
            for (int i = 0; i < 4; i++)
                acc[i][j] = __builtin_amdgcn_mfma_f32_16x16x32_bf16(af[i], bfv, acc[i][j], 0, 0, 0);
        }
        __syncthreads();
    }

    const float* bias = b2 + e * DM;
#pragma unroll
    for (int j = 0; j < 4; j++) {
        int n = n0 + wn * 64 + j * 16 + l16;
        float bj = bias[n];
#pragma unroll
        for (int i = 0; i < 4; i++) {
            int row = row0 + wm * 64 + i * 16 + quad * 4;
#pragma unroll
            for (int r = 0; r < 4; r++) {
                int tk = list[row + r];
                if (tk >= 0)
                    atomicAdd(&out[(size_t)tk * DM + n], acc[i][j][r] + bj);
            }
        }
    }
}

extern "C" void kernel_launch(void* const* d_in, const int* in_sizes, int n_in,
                              void* d_out, int out_size, void* d_ws, size_t ws_size,
                              hipStream_t stream)
{
    const float* x  = (const float*)d_in[0];
    const float* Wg = (const float*)d_in[1];
    const float* bg = (const float*)d_in[2];
    const float* W1 = (const float*)d_in[3];
    const float* b1 = (const float*)d_in[4];
    const float* W2 = (const float*)d_in[5];
    const float* b2 = (const float*)d_in[6];
    float* out = (float*)d_out;

    char* ws = (char*)d_ws;
    int* counts  = (int*)(ws + 0);            // 8 ints
    int* offsets = (int*)(ws + 64);           // 9 ints
    int* topk    = (int*)(ws + 256);          // 8192 ints
    int* list    = (int*)(ws + 33024);        // 9216 ints
    unsigned short* xb = (unsigned short*)(ws + (1u << 20));           // 8 MB
    unsigned short* WT = (unsigned short*)(ws + (16u << 20));          // 64 MB (W1T then W2T)
    unsigned short* Hb = (unsigned short*)(ws + (80u << 20));          // 75.5 MB

    hipMemsetAsync(counts, 0, NE * sizeof(int), stream);
    hipMemsetAsync(d_out, 0, (size_t)out_size * sizeof(float), stream);

    gate_kernel<<<T_TOKENS / 4, 256, 0, stream>>>(x, Wg, bg, counts, topk, xb);
    scatter_kernel<<<1, 256, 0, stream>>>(counts, topk, offsets, list);

    // W1: [e][K=DM][N=DF] -> [e][DF][DM]
    tr_cvt_kernel<<<dim3(DF / 64, DM / 256, NE), 256, 0, stream>>>(W1, WT, DM, DF);
    gemm1_kernel<<<dim3((MAXROWS / 128) * (DF / 128)), 256, 0, stream>>>(
        xb, WT, b1, offsets, list, Hb);

    // W2: [e][K=DF][N=DM] -> [e][DM][DF]  (reuses WT buffer; stream serializes)
    tr_cvt_kernel<<<dim3(DM / 64, DF / 256, NE), 256, 0, stream>>>(W2, WT, DF, DM);
    gemm2_kernel<<<dim3((MAXROWS / 128) * (DM / 128)), 256, 0, stream>>>(
        Hb, WT, b2, offsets, list, out);
}

// Round 8
// 656.885 us; speedup vs baseline: 1.1051x; 1.0115x over previous
//
#include <hip/hip_runtime.h>
#include <hip/hip_bf16.h>

#define T_TOKENS 4096
#define DM 1024
#define DF 4096
#define NE 8
#define MAXROWS 9216   // 8192 + 8*128 padding

typedef float f32x4 __attribute__((ext_vector_type(4)));
typedef short bf16x8 __attribute__((ext_vector_type(8)));

__device__ __forceinline__ unsigned short f2bf(float f) {
    union { float f; unsigned int u; } v; v.f = f;
    unsigned int r = v.u + 0x7fffu + ((v.u >> 16) & 1u);
    return (unsigned short)(r >> 16);
}

// async global->LDS, 16B per lane; LDS dest = wave-uniform base + lane*16
__device__ __forceinline__ void g2l16(const void* g, void* l) {
    __builtin_amdgcn_global_load_lds(
        (const __attribute__((address_space(1))) void*)g,
        (__attribute__((address_space(3))) void*)l, 16, 0, 0);
}

// ------- gating: logits -> top2 (softmax monotone, skip it); also emits x in bf16 ----
__global__ __launch_bounds__(256) void gate_kernel(
    const float* __restrict__ x, const float* __restrict__ Wg, const float* __restrict__ bg,
    int* __restrict__ counts, int* __restrict__ topk, unsigned short* __restrict__ xb)
{
    int wave = threadIdx.x >> 6;
    int lane = threadIdx.x & 63;
    int t = blockIdx.x * 4 + wave;
    float acc[NE];
#pragma unroll
    for (int e = 0; e < NE; e++) acc[e] = 0.f;
    const float* xr = x + (size_t)t * DM;
    unsigned short* xbr = xb + (size_t)t * DM;
#pragma unroll
    for (int i = 0; i < DM / 64; i++) {
        int d = lane + i * 64;
        float xv = xr[d];
        xbr[d] = f2bf(xv);                    // fused cvt_x
        const float4* wg = (const float4*)(Wg + d * NE);
        float4 w0 = wg[0], w1 = wg[1];
        acc[0] += xv * w0.x; acc[1] += xv * w0.y; acc[2] += xv * w0.z; acc[3] += xv * w0.w;
        acc[4] += xv * w1.x; acc[5] += xv * w1.y; acc[6] += xv * w1.z; acc[7] += xv * w1.w;
    }
#pragma unroll
    for (int e = 0; e < NE; e++) {
#pragma unroll
        for (int off = 32; off > 0; off >>= 1)
            acc[e] += __shfl_down(acc[e], off);
    }
    if (lane == 0) {
        float lg[NE];
#pragma unroll
        for (int e = 0; e < NE; e++) lg[e] = acc[e] + bg[e];
        int b1i = 0; float b1v = lg[0];
        for (int e = 1; e < NE; e++) if (lg[e] > b1v) { b1v = lg[e]; b1i = e; }
        int b2i = -1; float b2v = -1e30f;
        for (int e = 0; e < NE; e++) {
            if (e == b1i) continue;
            if (b2i < 0 || lg[e] > b2v) { b2v = lg[e]; b2i = e; }
        }
        topk[t * 2 + 0] = b1i;
        topk[t * 2 + 1] = b2i;
        atomicAdd(&counts[b1i], 1);
        atomicAdd(&counts[b2i], 1);
    }
}

// ---------------- per-expert token lists, segments padded to 128 rows ----------------
__global__ __launch_bounds__(256) void scatter_kernel(
    const int* __restrict__ counts, const int* __restrict__ topk,
    int* __restrict__ offsets, int* __restrict__ list)
{
    __shared__ int offs[NE + 1];
    __shared__ int cur[NE];
    if (threadIdx.x == 0) {
        int s = 0;
        for (int e = 0; e < NE; e++) {
            offs[e] = s; offsets[e] = s;
            s += (counts[e] + 127) & ~127;
        }
        offs[NE] = s; offsets[NE] = s;
    }
    if (threadIdx.x < NE) cur[threadIdx.x] = 0;
    __syncthreads();
    for (int i = threadIdx.x; i < T_TOKENS * 2; i += 256) {
        int e = topk[i];
        int pos = atomicAdd(&cur[e], 1);
        list[offs[e] + pos] = i >> 1;
    }
    __syncthreads();
    for (int e = 0; e < NE; e++) {
        int s = offs[e] + counts[e];
        int t = offs[e + 1];
        for (int i = s + threadIdx.x; i < t; i += 256) list[i] = -1;
    }
}

// ------- W [e][K][N] fp32 -> TILED bf16: WT[e][n32][k32][1024] -------------------
// tile[h*512 + l*8 + j] = W[k32*32 + 8*((l&3)^(((l>>2)>>1)&3)) + j][n32*32 + 16h + (l>>2)]
// i.e. exactly the 1KB image one g2l16 wave stages in the GEMM (source swizzle baked in).
// Block = [32 k x 1024 n] slab: reads 32 contiguous 4KB rows, writes contiguous tiles.
__global__ __launch_bounds__(256) void tr_cvt_tiled_kernel(
    const float* __restrict__ src, unsigned short* __restrict__ dst, int K, int N)
{
    const int e = blockIdx.z;
    src += (size_t)e * K * N;
    dst += (size_t)e * N * K;
    const int k0 = blockIdx.y * 32;
    const int k32 = blockIdx.y;
    const int nslab = blockIdx.x * 1024;
    const int K32 = K >> 5;

    __shared__ unsigned short tl[32][264];   // [k_rel][n_rel] bf16, 16.5 KB

    const int t = threadIdx.x;
    const int rquart = t >> 6;       // 0..3: row group for reads
    const int col4 = (t & 63) * 4;   // n offset within 256-chunk
    const int g = t >> 5;            // 0..7: output tile within chunk
    const int q = t & 31;
    const int kg = (q & 3) ^ (((q >> 2) >> 1) & 3);   // baked source swizzle

    for (int c = 0; c < 4; c++) {
        const int nbase = nslab + c * 256;
        // read: 32 rows x 256 n fp32, contiguous 1KB wave segments within 4KB rows
#pragma unroll
        for (int rr = 0; rr < 8; rr++) {
            int row = rr * 4 + rquart;
            float4 v = *(const float4*)(src + (size_t)(k0 + row) * N + nbase + col4);
            unsigned short o[4] = { f2bf(v.x), f2bf(v.y), f2bf(v.z), f2bf(v.w) };
            *(uint2*)&tl[row][col4] = *(const uint2*)o;
        }
        __syncthreads();
        // write: 8 tiles x 1KB, fully contiguous 512B per instruction
        const int n32 = (nbase >> 5) + g;
        unsigned short* dt = dst + ((size_t)n32 * K32 + k32) * 1024;
#pragma unroll
        for (int h = 0; h < 2; h++) {
#pragma unroll
            for (int p = 0; p < 2; p++) {
                int l = q + 32 * p;
                int nr = 32 * g + 16 * h + (l >> 2);
                unsigned short tmp[8];
#pragma unroll
                for (int j = 0; j < 8; j++) tmp[j] = tl[8 * kg + j][nr];
                *(uint4*)(dt + h * 512 + l * 8) = *(const uint4*)tmp;
            }
        }
        __syncthreads();
    }
}

// ---------------- GEMM1: H = relu(gather(xb) @ W1T^T + b1), all experts fused ------
// r0 structure (128x128, BK=32); expert-major-per-XCD work order; tiled-B stream
__global__ __launch_bounds__(256) void gemm1_kernel(
    const unsigned short* __restrict__ xb, const unsigned short* __restrict__ W1T,
    const float* __restrict__ b1, const int* __restrict__ offsets,
    const int* __restrict__ list, unsigned short* __restrict__ H)
{
    const int bid = blockIdx.x;                 // 2304 = 8 * 288
    const int W = (bid & 7) * 288 + (bid >> 3); // bijective
    const int bx = W >> 5;                      // row-block 0..71 (expert-contiguous)
    const int by = W & 31;                      // n-panel 0..31

    const int total = offsets[NE];
    const int row0 = bx * 128;
    if (row0 >= total) return;
    int e = 0;
    while (row0 >= offsets[e + 1]) e++;
    const int n0 = by * 128;

    __shared__ unsigned short Asm[128 * 32];
    __shared__ unsigned short Bsm[128 * 32];

    const int tid = threadIdx.x;
    const int w = tid >> 6, lane = tid & 63;
    const int quad = lane >> 4, l16 = lane & 15;
    const int wm = w >> 1, wn = w & 1;

    const int sr = lane >> 2;                              // row within 16-row chunk
    const int sc = (((lane & 3) ^ ((sr >> 1) & 3))) * 8;   // swizzled k source offset (A)
    const int qx8 = (quad ^ ((l16 >> 1) & 3)) * 8;         // swizzled k read offset

    const int ra1 = 32 * w + sr, ra2 = ra1 + 16;
    int t1 = list[row0 + ra1]; if (t1 < 0) t1 = 0;
    int t2 = list[row0 + ra2]; if (t2 < 0) t2 = 0;
    const unsigned short* gA1 = xb + (size_t)t1 * DM + sc;
    const unsigned short* gA2 = xb + (size_t)t2 * DM + sc;
    // tiled B: wave w owns n32 = n0/32 + w; 2KB per k-step, sequential
    const unsigned short* gB1 = W1T + (size_t)e * DF * DM
        + ((size_t)(n0 / 32 + w) * (DM / 32)) * 1024 + lane * 8;
    unsigned short* lA1 = Asm + (2 * w) * 512;
    unsigned short* lA2 = Asm + (2 * w + 1) * 512;
    unsigned short* lB1 = Bsm + (2 * w) * 512;
    unsigned short* lB2 = Bsm + (2 * w + 1) * 512;

    f32x4 acc[4][4];
#pragma unroll
    for (int i = 0; i < 4; i++)
#pragma unroll
        for (int j = 0; j < 4; j++) acc[i][j] = (f32x4){0.f, 0.f, 0.f, 0.f};

    for (int kk = 0; kk < DM; kk += 32) {
        g2l16(gA1 + kk, lA1);
        g2l16(gA2 + kk, lA2);
        g2l16(gB1 + kk * 32, lB1);
        g2l16(gB1 + kk * 32 + 512, lB2);
        __syncthreads();
        bf16x8 af[4];
#pragma unroll
        for (int i = 0; i < 4; i++)
            af[i] = *(const bf16x8*)&Asm[(wm * 64 + i * 16 + l16) * 32 + qx8];
#pragma unroll
        for (int j = 0; j < 4; j++) {
            bf16x8 bfv = *(const bf16x8*)&Bsm[(wn * 64 + j * 16 + l16) * 32 + qx8];
#pragma unroll
            for (int i = 0; i < 4; i++)
                acc[i][j] = __builtin_amdgcn_mfma_f32_16x16x32_bf16(af[i], bfv, acc[i][j], 0, 0, 0);
        }
        __syncthreads();
    }

    const float* bias = b1 + e * DF;
#pragma unroll
    for (int j = 0; j < 4; j++) {
        int n = n0 + wn * 64 + j * 16 + l16;
        float bj = bias[n];
#pragma unroll
        for (int i = 0; i < 4; i++) {
            int row = row0 + wm * 64 + i * 16 + quad * 4;
#pragma unroll
            for (int r = 0; r < 4; r++) {
                float v = acc[i][j][r] + bj;
                v = fmaxf(v, 0.f);
                H[(size_t)(row + r) * DF + n] = f2bf(v);
            }
        }
    }
}

// ---------------- GEMM2: out[tok] += H @ W2T^T + b2, all experts fused -------------
// r0 structure (128x128, BK=32); expert-major-per-XCD work order; tiled-B stream
__global__ __launch_bounds__(256) void gemm2_kernel(
    const unsigned short* __restrict__ H, const unsigned short* __restrict__ W2T,
    const float* __restrict__ b2, const int* __restrict__ offsets,
    const int* __restrict__ list, float* __restrict__ out)
{
    const int bid = blockIdx.x;                // 576 = 8 * 72
    const int W = (bid & 7) * 72 + (bid >> 3); // bijective
    const int bx = W >> 3;                     // row-block 0..71 (expert-contiguous)
    const int by = W & 7;                      // n-panel 0..7

    const int total = offsets[NE];
    const int row0 = bx * 128;
    if (row0 >= total) return;
    int e = 0;
    while (row0 >= offsets[e + 1]) e++;
    const int n0 = by * 128;

    __shared__ unsigned short Asm[128 * 32];
    __shared__ unsigned short Bsm[128 * 32];

    const int tid = threadIdx.x;
    const int w = tid >> 6, lane = tid & 63;
    const int quad = lane >> 4, l16 = lane & 15;
    const int wm = w >> 1, wn = w & 1;

    const int sr = lane >> 2;
    const int sc = (((lane & 3) ^ ((sr >> 1) & 3))) * 8;
    const int qx8 = (quad ^ ((l16 >> 1) & 3)) * 8;

    const unsigned short* gA1 = H + (size_t)(row0 + 32 * w + sr) * DF + sc;
    const unsigned short* gA2 = gA1 + (size_t)16 * DF;
    const unsigned short* gB1 = W2T + (size_t)e * DM * DF
        + ((size_t)(n0 / 32 + w) * (DF / 32)) * 1024 + lane * 8;
    unsigned short* lA1 = Asm + (2 * w) * 512;
    unsigned short* lA2 = Asm + (2 * w + 1) * 512;
    unsigned short* lB1 = Bsm + (2 * w) * 512;
    unsigned short* lB2 = Bsm + (2 * w + 1) * 512;

    f32x4 acc[4][4];
#pragma unroll
    for (int i = 0; i < 4; i++)
#pragma unroll
        for (int j = 0; j < 4; j++) acc[i][j] = (f32x4){0.f, 0.f, 0.f, 0.f};

    for (int kk = 0; kk < DF; kk += 32) {
        g2l16(gA1 + kk, lA1);
        g2l16(gA2 + kk, lA2);
        g2l16(gB1 + kk * 32, lB1);
        g2l16(gB1 + kk * 32 + 512, lB2);
        __syncthreads();
        bf16x8 af[4];
#pragma unroll
        for (int i = 0; i < 4; i++)
            af[i] = *(const bf16x8*)&Asm[(wm * 64 + i * 16 + l16) * 32 + qx8];
#pragma unroll
        for (int j = 0; j < 4; j++) {
            bf16x8 bfv = *(const bf16x8*)&Bsm[(wn * 64 + j * 16 + l16) * 32 + qx8];
#pragma unroll
            for (int i = 0; i < 4; i++)
                acc[i][j] = __builtin_amdgcn_mfma_f32_16x16x32_bf16(af[i], bfv, acc[i][j], 0, 0, 0);
        }
        __syncthreads();
    }

    const float* bias = b2 + e * DM;
#pragma unroll
    for (int j = 0; j < 4; j++) {
        int n = n0 + wn * 64 + j * 16 + l16;
        float bj = bias[n];
#pragma unroll
        for (int i = 0; i < 4; i++) {
            int row = row0 + wm * 64 + i * 16 + quad * 4;
#pragma unroll
            for (int r = 0; r < 4; r++) {
                int tk = list[row + r];
                if (tk >= 0)
                    atomicAdd(&out[(size_t)tk * DM + n], acc[i][j][r] + bj);
            }
        }
    }
}

extern "C" void kernel_launch(void* const* d_in, const int* in_sizes, int n_in,
                              void* d_out, int out_size, void* d_ws, size_t ws_size,
                              hipStream_t stream)
{
    const float* x  = (const float*)d_in[0];
    const float* Wg = (const float*)d_in[1];
    const float* bg = (const float*)d_in[2];
    const float* W1 = (const float*)d_in[3];
    const float* b1 = (const float*)d_in[4];
    const float* W2 = (const float*)d_in[5];
    const float* b2 = (const float*)d_in[6];
    float* out = (float*)d_out;

    char* ws = (char*)d_ws;
    int* counts  = (int*)(ws + 0);            // 8 ints
    int* offsets = (int*)(ws + 64);           // 9 ints
    int* topk    = (int*)(ws + 256);          // 8192 ints
    int* list    = (int*)(ws + 33024);        // 9216 ints
    unsigned short* xb = (unsigned short*)(ws + (1u << 20));           // 8 MB
    unsigned short* WT = (unsigned short*)(ws + (16u << 20));          // 64 MB (W1T then W2T)
    unsigned short* Hb = (unsigned short*)(ws + (80u << 20));          // 75.5 MB

    hipMemsetAsync(counts, 0, NE * sizeof(int), stream);
    hipMemsetAsync(d_out, 0, (size_t)out_size * sizeof(float), stream);

    gate_kernel<<<T_TOKENS / 4, 256, 0, stream>>>(x, Wg, bg, counts, topk, xb);
    scatter_kernel<<<1, 256, 0, stream>>>(counts, topk, offsets, list);

    // W1 [e][DM][DF] fp32 -> tiled bf16 [e][n32][k32][1024], K=DM, N=DF
    tr_cvt_tiled_kernel<<<dim3(DF / 1024, DM / 32, NE), 256, 0, stream>>>(W1, WT, DM, DF);
    gemm1_kernel<<<dim3((MAXROWS / 128) * (DF / 128)), 256, 0, stream>>>(
        xb, WT, b1, offsets, list, Hb);

    // W2 [e][DF][DM] fp32 -> tiled bf16, K=DF, N=DM (reuses WT; stream serializes)
    tr_cvt_tiled_kernel<<<dim3(DM / 1024, DF / 32, NE), 256, 0, stream>>>(W2, WT, DF, DM);
    gemm2_kernel<<<dim3((MAXROWS / 128) * (DM / 128)), 256, 0, stream>>>(
        Hb, WT, b2, offsets, list, out);
}